// Round 20
// baseline (465.528 us; speedup 1.0000x reference)
//
#include <hip/hip_runtime.h>
#include <hip/hip_bf16.h>

#define NN 768
#define CSD 384
#define CZD 128
#define HD 12
#define DOUT 2112
#define II 2

#define SCALE_SINGLE 0.25f
#define SCALE_FRAME (-0.11785113019775793f)   /* -1/sqrt(72) */

// bf16 weight pool offsets (ushort elems) — TRANSPOSED layouts:
// proj families: [col][r] (r=0..383 contiguous); Wout: [c][d] (d=0..2111 contiguous)
#define OFF_WQ   0
#define OFF_WK   73728
#define OFF_WV   147456
#define OFF_WQP  221184
#define OFF_WKP  276480
#define OFF_WVP  331776
#define OFF_WOUT 442368
#define NBF_TOTAL 1253376   /* 442368 + 811008 */

__device__ __forceinline__ float dot4f(float4 a, float4 b){
    return fmaf(a.x,b.x, fmaf(a.y,b.y, fmaf(a.z,b.z, a.w*b.w)));
}
__device__ __forceinline__ unsigned short f2bf(float f){   // fp32 -> bf16 (RNE)
    unsigned u = __float_as_uint(f);
    return (unsigned short)((u + 0x7fffu + ((u >> 16) & 1u)) >> 16);
}
__device__ __forceinline__ float bf_lo32(unsigned u){ return __uint_as_float(u << 16); }
__device__ __forceinline__ float bf_hi32(unsigned u){ return __uint_as_float(u & 0xffff0000u); }
__device__ __forceinline__ void unpack8(uint4 v, float* w){
    w[0]=bf_lo32(v.x); w[1]=bf_hi32(v.x); w[2]=bf_lo32(v.y); w[3]=bf_hi32(v.y);
    w[4]=bf_lo32(v.z); w[5]=bf_hi32(v.z); w[6]=bf_lo32(v.w); w[7]=bf_hi32(v.w);
}

// ---------------- K0: one-shot weight conversion fp32 -> bf16 TRANSPOSED ----------------
__global__ __launch_bounds__(256) void k_conv(
    const float* __restrict__ Wq, const float* __restrict__ Wk, const float* __restrict__ Wv,
    const float* __restrict__ Wqp, const float* __restrict__ Wkp, const float* __restrict__ Wvp,
    const float* __restrict__ Wout, unsigned short* __restrict__ dst)
{
    int idx = blockIdx.x*256 + threadIdx.x;
    if (idx >= NBF_TOTAL) return;
    if (idx >= OFF_WOUT){
        int off = idx - OFF_WOUT;
        int c = off / DOUT, d = off % DOUT;          // dst[c][d] = Wout[d][c]
        dst[idx] = f2bf(Wout[(size_t)d*CSD + c]);
        return;
    }
    const float* src; int off = idx; int ncol;
    if (idx < OFF_WK)        { src = Wq;  ncol=192; }
    else if (idx < OFF_WV)   { src = Wk;  off -= OFF_WK;  ncol=192; }
    else if (idx < OFF_WQP)  { src = Wv;  off -= OFF_WV;  ncol=192; }
    else if (idx < OFF_WKP)  { src = Wqp; off -= OFF_WQP; ncol=144; }
    else if (idx < OFF_WVP)  { src = Wkp; off -= OFF_WKP; ncol=144; }
    else                     { src = Wvp; off -= OFF_WVP; ncol=288; }
    int c = off / CSD, r = off % CSD;                // dst[c][r] = W[r][c]
    dst[idx] = f2bf(src[(size_t)r*ncol + c]);
}

// ---------------- K1: projections + frame apply, II=2, vectorized bf16 stream ----------------
__global__ __launch_bounds__(384) void k_proj(
    const float* __restrict__ s, const float* __restrict__ R, const float* __restrict__ tv,
    const unsigned short* __restrict__ wbf,
    float* __restrict__ q, float* __restrict__ k, float* __restrict__ v,
    float* __restrict__ gq, float* __restrict__ gk, float* __restrict__ gv,
    float* __restrict__ sqq, float* __restrict__ sqk)
{
    __shared__ float s_l[II*CSD];
    __shared__ float praw[II][576];
    __shared__ float sq_pt[II][96];
    int i0 = blockIdx.x * II, t = threadIdx.x;
    if (t < II*CSD/4){
        const float4* s4 = (const float4*)(s + (size_t)i0*CSD);
        ((float4*)s_l)[t] = s4[t];
    }
    __syncthreads();

    int cols[3] = {t, t+384, t+768};
    const unsigned short* WT[3];
    #pragma unroll
    for (int m=0;m<3;m++){
        int c = cols[m];
        if (c < 192)       WT[m] = wbf + OFF_WQ  + (size_t)c*CSD;
        else if (c < 384)  WT[m] = wbf + OFF_WK  + (size_t)(c-192)*CSD;
        else if (c < 576)  WT[m] = wbf + OFF_WV  + (size_t)(c-384)*CSD;
        else if (c < 720)  WT[m] = wbf + OFF_WQP + (size_t)(c-576)*CSD;
        else if (c < 864)  WT[m] = wbf + OFF_WKP + (size_t)(c-720)*CSD;
        else               WT[m] = wbf + OFF_WVP + (size_t)(c-864)*CSD;
    }
    float acc[3][II];
    #pragma unroll
    for (int m=0;m<3;m++)
        #pragma unroll
        for (int ii=0;ii<II;ii++) acc[m][ii]=0.f;

    for (int r8=0; r8<CSD; r8+=8){
        uint4 v0 = *(const uint4*)(WT[0] + r8);
        uint4 v1 = *(const uint4*)(WT[1] + r8);
        uint4 v2 = *(const uint4*)(WT[2] + r8);
        float w0[8], w1[8], w2[8];
        unpack8(v0, w0); unpack8(v1, w1); unpack8(v2, w2);
        #pragma unroll
        for (int u=0; u<8; ++u){
            #pragma unroll
            for (int ii=0;ii<II;ii++){
                float sv = s_l[ii*CSD + r8 + u];
                acc[0][ii] = fmaf(sv, w0[u], acc[0][ii]);
                acc[1][ii] = fmaf(sv, w1[u], acc[1][ii]);
                acc[2][ii] = fmaf(sv, w2[u], acc[2][ii]);
            }
        }
    }
    #pragma unroll
    for (int m=0;m<3;m++){
        int c = cols[m];
        #pragma unroll
        for (int ii=0;ii<II;ii++){
            float val = acc[m][ii];
            size_t i = i0 + ii;
            if (c < 192) q[i*192 + c] = val;
            else if (c < 384) k[i*192 + (c-192)] = val;
            else if (c < 576) v[i*192 + (c-384)] = val;
            else praw[ii][c-576] = val;
        }
    }
    __syncthreads();

    if (t < 192){
        #pragma unroll
        for (int ii=0;ii<II;ii++){
            size_t i = i0 + ii;
            const float* Ri = R + i*9;
            float R00=Ri[0],R01=Ri[1],R02=Ri[2];
            float R10=Ri[3],R11=Ri[4],R12=Ri[5];
            float R20=Ri[6],R21=Ri[7],R22=Ri[8];
            float t0=tv[i*3+0],t1=tv[i*3+1],t2=tv[i*3+2];
            int src; float* dst; int sqslot=-1;
            if (t < 48){ src = t*3; dst = gq + i*144 + t*3; sqslot = t; }
            else if (t < 96){ int u=t-48; src = 144+u*3; dst = gk + i*144 + u*3; sqslot = 48+u; }
            else { int u=t-96; src = 288+u*3; dst = gv + i*288 + u*3; }
            float x=praw[ii][src], y=praw[ii][src+1], zc=praw[ii][src+2];
            float g0 = fmaf(R00,x, fmaf(R01,y, fmaf(R02,zc, t0)));
            float g1 = fmaf(R10,x, fmaf(R11,y, fmaf(R12,zc, t1)));
            float g2 = fmaf(R20,x, fmaf(R21,y, fmaf(R22,zc, t2)));
            dst[0]=g0; dst[1]=g1; dst[2]=g2;
            if (sqslot >= 0) sq_pt[ii][sqslot] = g0*g0 + g1*g1 + g2*g2;
        }
    }
    __syncthreads();
    if (t < II*HD){
        int ii = t / HD, h = t % HD;
        float s1 = sq_pt[ii][h*4]+sq_pt[ii][h*4+1]+sq_pt[ii][h*4+2]+sq_pt[ii][h*4+3];
        float s2 = sq_pt[ii][48+h*4]+sq_pt[ii][48+h*4+1]+sq_pt[ii][48+h*4+2]+sq_pt[ii][48+h*4+3];
        sqq[(size_t)(i0+ii)*HD + h] = s1;
        sqk[(size_t)(i0+ii)*HD + h] = s2;
    }
}

// ---------------- K2: fused IPA (R19 verbatim — measured best 313 us) ----------------
__global__ __launch_bounds__(512) void k_ipa(
    const float* __restrict__ z, const float* __restrict__ Wb, const float* __restrict__ scale_head,
    const float* __restrict__ q, const float* __restrict__ k,
    const float* __restrict__ gq, const float* __restrict__ gk,
    const float* __restrict__ sqq, const float* __restrict__ sqk,
    const float* __restrict__ v, const float* __restrict__ gv,
    const float* __restrict__ R, const float* __restrict__ tv,
    float* __restrict__ att)
{
    __shared__ float ztile[2][64][CZD];
    __shared__ float wbT[HD*CZD];
    __shared__ float qloc[360];
    __shared__ float a_l[HD][NN];
    __shared__ float so_l[288];

    int i = blockIdx.x, t = threadIdx.x;
    int wave = t >> 6, lane = t & 63;

    for (int idx=t; idx<HD*CZD; idx+=512){
        int h = idx >> 7, c = idx & 127;
        wbT[idx] = Wb[(size_t)c*HD + h];
    }
    if (t < 192) qloc[t] = q[(size_t)i*192 + t];
    else if (t < 336) qloc[t] = gq[(size_t)i*144 + (t-192)];
    else if (t < 348) qloc[t] = sqq[(size_t)i*HD + (t-336)];
    else if (t < 360){
        int h = t-348;
        float shv = scale_head[h];
        float sp = (shv > 20.f) ? shv : log1pf(__expf(shv));
        qloc[t] = SCALE_FRAME * sp;
    }

    const char* zi = (const char*)(z + (size_t)i*NN*CZD);
    float* zbase = &ztile[0][0][0];

#define STAGEL(JT, BUF) do { \
    const char* _zb = zi + (size_t)(JT)*32768; \
    char* _lb = (char*)zbase + (size_t)(BUF)*32768; \
    _Pragma("unroll") \
    for (int _m=0;_m<4;_m++){ \
        int _d = t*16 + _m*8192; \
        int _j = _d >> 9; \
        int _b = _d & 511; \
        int _sb = _b ^ ((_j & 31) << 4); \
        __builtin_amdgcn_global_load_lds((const __attribute__((address_space(1))) void*)(_zb + (size_t)_j*512 + _sb), \
            (__attribute__((address_space(3))) void*)(_lb + _d), 16, 0, 0); \
    } \
  } while(0)

#define STAGEB(JT, BUF) do { \
    const char* _zb = zi + (size_t)(JT)*32768; \
    char* _lb = (char*)zbase + (size_t)(BUF)*32768; \
    _Pragma("unroll") \
    for (int _m=0;_m<4;_m++){ \
        int _d = t*16 + _m*8192; \
        __builtin_amdgcn_global_load_lds((const __attribute__((address_space(1))) void*)(_zb + _d), \
            (__attribute__((address_space(3))) void*)(_lb + _d), 16, 0, 0); \
    } \
  } while(0)

    STAGEL(0, 0);

    int hg = (wave < 4) ? wave : (wave - 4);
    int h0 = hg * 3;
    float L[12][3];

    __syncthreads();

    {
        const float4* wb4 = (const float4*)wbT;
        const float4* qv4 = (const float4*)qloc;
        const float4* gq4 = (const float4*)(qloc + 192);
        int xoff = (lane & 31) << 4;

        for (int jt=0; jt<12; ++jt){
            int cur = jt & 1;
            if (jt+1 < 12) STAGEL(jt+1, cur^1);
            if (wave < 4){
                const char* zb = (const char*)(zbase + (size_t)cur*8192) + lane*512;
                float p0=0.f, p1=0.f, p2=0.f;
                #pragma unroll 8
                for (int c4=0; c4<32; ++c4){
                    float4 zv = *(const float4*)(zb + ((c4*16) ^ xoff));
                    p0 += dot4f(zv, wb4[(h0+0)*32 + c4]);
                    p1 += dot4f(zv, wb4[(h0+1)*32 + c4]);
                    p2 += dot4f(zv, wb4[(h0+2)*32 + c4]);
                }
                L[jt][0]=p0; L[jt][1]=p1; L[jt][2]=p2;
            } else {
                int jg = jt*64 + lane;
                const float4* kp  = (const float4*)(k  + (size_t)jg*192);
                const float4* gkp = (const float4*)(gk + (size_t)jg*144);
                #pragma unroll
                for (int hs=0; hs<3; ++hs){
                    int h = h0 + hs;
                    float sng = dot4f(qv4[h*4+0], kp[h*4+0]) + dot4f(qv4[h*4+1], kp[h*4+1])
                              + dot4f(qv4[h*4+2], kp[h*4+2]) + dot4f(qv4[h*4+3], kp[h*4+3]);
                    float fdot = dot4f(gq4[h*3+0], gkp[h*3+0]) + dot4f(gq4[h*3+1], gkp[h*3+1])
                               + dot4f(gq4[h*3+2], gkp[h*3+2]);
                    float d2 = qloc[336+h] + sqk[(size_t)jg*HD + h] - 2.0f*fdot;
                    L[jt][hs] = fmaf(SCALE_SINGLE, sng, qloc[348+h]*d2);
                }
            }
            __syncthreads();
        }
    }

    float* S_l = zbase;
    if (wave >= 4){
        int base = (hg*64 + lane) * 37;
        #pragma unroll
        for (int jt=0; jt<12; ++jt)
            #pragma unroll
            for (int hs=0; hs<3; ++hs)
                S_l[base + jt*3 + hs] = L[jt][hs];
    }
    __syncthreads();
    if (wave < 4){
        int base = (hg*64 + lane) * 37;
        #pragma unroll
        for (int jt=0; jt<12; ++jt)
            #pragma unroll
            for (int hs=0; hs<3; ++hs)
                L[jt][hs] += S_l[base + jt*3 + hs];

        #pragma unroll
        for (int hs=0; hs<3; ++hs){
            float m = -1e30f;
            #pragma unroll
            for (int jt=0; jt<12; ++jt) m = fmaxf(m, L[jt][hs]);
            #pragma unroll
            for (int off=32; off; off>>=1) m = fmaxf(m, __shfl_xor(m, off));
            float ssum = 0.f;
            #pragma unroll
            for (int jt=0; jt<12; ++jt){ float e = __expf(L[jt][hs]-m); L[jt][hs]=e; ssum += e; }
            #pragma unroll
            for (int off=32; off; off>>=1) ssum += __shfl_xor(ssum, off);
            float inv = 1.0f/ssum;
            #pragma unroll
            for (int jt=0; jt<12; ++jt){
                a_l[h0+hs][jt*64 + lane] = L[jt][hs]*inv;
            }
        }
    }
    __syncthreads();

    STAGEB(0, 0);

    int hs = 0;
    const float4* gsrc = nullptr;
    int gstride = 0;
    if (t < 384){ hs = t>>5; }
    else if (t < 432){ int u=t-384; hs = u>>2; gsrc = (const float4*)v  + hs*4 + (u&3); gstride = 48; }
    else if (t < 504){ int u=t-432; hs = u/6;  gsrc = (const float4*)gv + hs*6 + (u%6); gstride = 72; }
    float4 acc = {0.f,0.f,0.f,0.f};
    int c4 = t & 31;

    __syncthreads();

    for (int jt=0; jt<12; ++jt){
        int cur = jt & 1;
        if (jt+1 < 12) STAGEB(jt+1, cur^1);
        if (t < 384){
            const float4* arow4 = (const float4*)&a_l[hs][0];
            float4 af[16];
            #pragma unroll
            for (int m=0;m<16;m++) af[m] = arow4[jt*16 + m];
            const float4* zt4 = (const float4*)(zbase + (size_t)cur*8192);
            #pragma unroll
            for (int jj=0;jj<64;jj++){
                float aw = ((const float*)af)[jj];
                float4 zv = zt4[jj*32 + c4];
                acc.x = fmaf(aw, zv.x, acc.x);
                acc.y = fmaf(aw, zv.y, acc.y);
                acc.z = fmaf(aw, zv.z, acc.z);
                acc.w = fmaf(aw, zv.w, acc.w);
            }
        } else if (t < 504){
            const float* arow = &a_l[hs][0];
            #pragma unroll
            for (int jj=0;jj<64;jj++){
                int j = jt*64 + jj;
                float aw = arow[j];
                float4 sv = gsrc[(size_t)j*gstride];
                acc.x = fmaf(aw, sv.x, acc.x);
                acc.y = fmaf(aw, sv.y, acc.y);
                acc.z = fmaf(aw, sv.z, acc.z);
                acc.w = fmaf(aw, sv.w, acc.w);
            }
        }
        __syncthreads();
    }

    if (t < 384){
        float4* dst = (float4*)(att + (size_t)i*DOUT + 192) + (hs*32 + c4);
        *dst = acc;
    } else if (t < 432){
        int u = t-384;
        float4* dst = (float4*)(att + (size_t)i*DOUT) + u;
        *dst = acc;
    } else if (t < 504){
        int u = t-432;
        ((float4*)so_l)[u] = acc;
    }
    __syncthreads();
    if (t < 96){
        int h = t >> 3, p = t & 7;
        float d0 = so_l[h*24+p*3+0] - tv[(size_t)i*3+0];
        float d1 = so_l[h*24+p*3+1] - tv[(size_t)i*3+1];
        float d2 = so_l[h*24+p*3+2] - tv[(size_t)i*3+2];
        const float* Ri = R + (size_t)i*9;
        float l0 = fmaf(Ri[0],d0, fmaf(Ri[3],d1, Ri[6]*d2));
        float l1 = fmaf(Ri[1],d0, fmaf(Ri[4],d1, Ri[7]*d2));
        float l2 = fmaf(Ri[2],d0, fmaf(Ri[5],d1, Ri[8]*d2));
        size_t base = (size_t)i*DOUT;
        att[base + 1728 + p*36 + h*3 + 0] = l0;
        att[base + 1728 + p*36 + h*3 + 1] = l1;
        att[base + 1728 + p*36 + h*3 + 2] = l2;
        att[base + 2016 + p*12 + h] = sqrtf(l0*l0 + l1*l1 + l2*l2);
    }
#undef STAGEL
#undef STAGEB
}

// ---------------- K4: final projection att @ WoutT(bf16, [c][d]) + bout ----------------
#define ROWS4 2
__global__ __launch_bounds__(384) void k_final(
    const float* __restrict__ att, const unsigned short* __restrict__ wobf,
    const float* __restrict__ bout, float* __restrict__ out)
{
    __shared__ float att_l[ROWS4*DOUT];
    int ib = blockIdx.x * ROWS4, t = threadIdx.x;
    for (int idx=t; idx<ROWS4*DOUT; idx+=384){
        att_l[idx] = att[(size_t)ib*DOUT + idx];
    }
    __syncthreads();
    const unsigned short* wc = wobf + (size_t)t*DOUT;   // this column's contiguous d-row
    float a0=0.f,a1=0.f,a2=0.f,a3=0.f;
    float b0=0.f,b1=0.f,b2=0.f,b3=0.f;
    #pragma unroll 4
    for (int d8=0; d8<DOUT; d8+=8){
        uint4 wv = *(const uint4*)(wc + d8);
        float w_[8]; unpack8(wv, w_);
        a0 = fmaf(att_l[d8+0], w_[0], a0);
        a1 = fmaf(att_l[d8+1], w_[1], a1);
        a2 = fmaf(att_l[d8+2], w_[2], a2);
        a3 = fmaf(att_l[d8+3], w_[3], a3);
        a0 = fmaf(att_l[d8+4], w_[4], a0);
        a1 = fmaf(att_l[d8+5], w_[5], a1);
        a2 = fmaf(att_l[d8+6], w_[6], a2);
        a3 = fmaf(att_l[d8+7], w_[7], a3);
        b0 = fmaf(att_l[DOUT+d8+0], w_[0], b0);
        b1 = fmaf(att_l[DOUT+d8+1], w_[1], b1);
        b2 = fmaf(att_l[DOUT+d8+2], w_[2], b2);
        b3 = fmaf(att_l[DOUT+d8+3], w_[3], b3);
        b0 = fmaf(att_l[DOUT+d8+4], w_[4], b0);
        b1 = fmaf(att_l[DOUT+d8+5], w_[5], b1);
        b2 = fmaf(att_l[DOUT+d8+6], w_[6], b2);
        b3 = fmaf(att_l[DOUT+d8+7], w_[7], b3);
    }
    float bb = bout[t];
    out[(size_t)ib*CSD + t]     = bb + ((a0+a1)+(a2+a3));
    out[(size_t)(ib+1)*CSD + t] = bb + ((b0+b1)+(b2+b3));
}

extern "C" void kernel_launch(void* const* d_in, const int* in_sizes, int n_in,
                              void* d_out, int out_size, void* d_ws, size_t ws_size,
                              hipStream_t stream)
{
    const float* s   = (const float*)d_in[0];
    const float* z   = (const float*)d_in[1];
    const float* R   = (const float*)d_in[2];
    const float* tv  = (const float*)d_in[3];
    const float* Wq  = (const float*)d_in[4];
    const float* Wk  = (const float*)d_in[5];
    const float* Wv  = (const float*)d_in[6];
    const float* Wqp = (const float*)d_in[7];
    const float* Wkp = (const float*)d_in[8];
    const float* Wvp = (const float*)d_in[9];
    const float* Wb  = (const float*)d_in[10];
    const float* Wout= (const float*)d_in[11];
    const float* bout= (const float*)d_in[12];
    const float* sh  = (const float*)d_in[13];

    float* ws  = (float*)d_ws;
    float* q_  = ws;                 // 768*192
    float* k_  = q_  + 147456;       // 768*192
    float* v_  = k_  + 147456;       // 768*192
    float* gq_ = v_  + 147456;       // 768*144
    float* gk_ = gq_ + 110592;       // 768*144
    float* gv_ = gk_ + 110592;       // 768*288
    float* sqq_= gv_ + 221184;       // 768*12
    float* sqk_= sqq_ + 9216;        // 768*12
    float* att_= sqk_ + 9216;        // 768*2112
    unsigned short* wbf = (unsigned short*)(att_ + 1622016);  // 1253376 ushorts
    float* out = (float*)d_out;

    hipLaunchKernelGGL(k_conv,  dim3((NBF_TOTAL+255)/256), dim3(256), 0, stream,
                       Wq,Wk,Wv,Wqp,Wkp,Wvp,Wout, wbf);
    hipLaunchKernelGGL(k_proj,  dim3(NN/II), dim3(384), 0, stream,
                       s,R,tv, wbf, q_,k_,v_,gq_,gk_,gv_,sqq_,sqk_);
    hipLaunchKernelGGL(k_ipa,   dim3(NN),    dim3(512), 0, stream,
                       z,Wb,sh,q_,k_,gq_,gk_,sqq_,sqk_, v_,gv_,R,tv, att_);
    hipLaunchKernelGGL(k_final, dim3(NN/ROWS4), dim3(384), 0, stream,
                       att_, wbf + OFF_WOUT, bout, out);
}

// Round 21
// 386.894 us; speedup vs baseline: 1.2032x; 1.2032x over previous
//
#include <hip/hip_runtime.h>
#include <hip/hip_bf16.h>

#define NN 768
#define CSD 384
#define CZD 128
#define HD 12
#define DOUT 2112
#define II 2

#define SCALE_SINGLE 0.25f
#define SCALE_FRAME (-0.11785113019775793f)   /* -1/sqrt(72) */

// bf16 weight pool offsets (ushort elems) — row-major (coalesced across lanes)
#define OFF_WQ   0
#define OFF_WK   73728
#define OFF_WV   147456
#define OFF_WQP  221184
#define OFF_WKP  276480
#define OFF_WVP  331776
#define OFF_WOUT 442368
#define NBF_TOTAL 1253376   /* 442368 + 811008 */

__device__ __forceinline__ float dot4f(float4 a, float4 b){
    return fmaf(a.x,b.x, fmaf(a.y,b.y, fmaf(a.z,b.z, a.w*b.w)));
}
__device__ __forceinline__ unsigned short f2bf(float f){   // fp32 -> bf16 (RNE)
    unsigned u = __float_as_uint(f);
    return (unsigned short)((u + 0x7fffu + ((u >> 16) & 1u)) >> 16);
}
__device__ __forceinline__ float bf2f(unsigned short u){
    return __uint_as_float(((unsigned)u) << 16);
}

// ---------------- K0: one-shot weight conversion fp32 -> bf16 into ws ----------------
__global__ __launch_bounds__(256) void k_conv(
    const float* __restrict__ Wq, const float* __restrict__ Wk, const float* __restrict__ Wv,
    const float* __restrict__ Wqp, const float* __restrict__ Wkp, const float* __restrict__ Wvp,
    const float* __restrict__ Wout, unsigned short* __restrict__ dst)
{
    int idx = blockIdx.x*256 + threadIdx.x;
    if (idx >= NBF_TOTAL) return;
    const float* src; int off = idx;
    if (idx < OFF_WK)        { src = Wq;  }
    else if (idx < OFF_WV)   { src = Wk;  off -= OFF_WK;  }
    else if (idx < OFF_WQP)  { src = Wv;  off -= OFF_WV;  }
    else if (idx < OFF_WKP)  { src = Wqp; off -= OFF_WQP; }
    else if (idx < OFF_WVP)  { src = Wkp; off -= OFF_WKP; }
    else if (idx < OFF_WOUT) { src = Wvp; off -= OFF_WVP; }
    else                     { src = Wout; off -= OFF_WOUT; }
    dst[idx] = f2bf(src[off]);
}

// ---------------- K1: projections + frame apply, II=2, bf16 weight stream ----------------
__global__ __launch_bounds__(384) void k_proj(
    const float* __restrict__ s, const float* __restrict__ R, const float* __restrict__ tv,
    const unsigned short* __restrict__ wbf,
    float* __restrict__ q, float* __restrict__ k, float* __restrict__ v,
    float* __restrict__ gq, float* __restrict__ gk, float* __restrict__ gv,
    float* __restrict__ sqq, float* __restrict__ sqk)
{
    __shared__ float s_l[II*CSD];
    __shared__ float praw[II][576];
    __shared__ float sq_pt[II][96];
    int i0 = blockIdx.x * II, t = threadIdx.x;
    if (t < II*CSD/4){
        const float4* s4 = (const float4*)(s + (size_t)i0*CSD);
        ((float4*)s_l)[t] = s4[t];
    }
    __syncthreads();

    int cols[3] = {t, t+384, t+768};
    const unsigned short* Wp[3]; int st[3], lc[3];
    #pragma unroll
    for (int m=0;m<3;m++){
        int c = cols[m];
        if (c < 192){ Wp[m]=wbf+OFF_WQ;  st[m]=192; lc[m]=c; }
        else if (c < 384){ Wp[m]=wbf+OFF_WK;  st[m]=192; lc[m]=c-192; }
        else if (c < 576){ Wp[m]=wbf+OFF_WV;  st[m]=192; lc[m]=c-384; }
        else if (c < 720){ Wp[m]=wbf+OFF_WQP; st[m]=144; lc[m]=c-576; }
        else if (c < 864){ Wp[m]=wbf+OFF_WKP; st[m]=144; lc[m]=c-720; }
        else { Wp[m]=wbf+OFF_WVP; st[m]=288; lc[m]=c-864; }
    }
    float acc[3][II];
    #pragma unroll
    for (int m=0;m<3;m++)
        #pragma unroll
        for (int ii=0;ii<II;ii++) acc[m][ii]=0.f;

    #pragma unroll 4
    for (int r=0;r<CSD;r++){
        float w0 = bf2f(Wp[0][(size_t)r*st[0]+lc[0]]);
        float w1 = bf2f(Wp[1][(size_t)r*st[1]+lc[1]]);
        float w2 = bf2f(Wp[2][(size_t)r*st[2]+lc[2]]);
        #pragma unroll
        for (int ii=0;ii<II;ii++){
            float sv = s_l[ii*CSD + r];
            acc[0][ii] = fmaf(sv, w0, acc[0][ii]);
            acc[1][ii] = fmaf(sv, w1, acc[1][ii]);
            acc[2][ii] = fmaf(sv, w2, acc[2][ii]);
        }
    }
    #pragma unroll
    for (int m=0;m<3;m++){
        int c = cols[m];
        #pragma unroll
        for (int ii=0;ii<II;ii++){
            float val = acc[m][ii];
            size_t i = i0 + ii;
            if (c < 192) q[i*192 + c] = val;
            else if (c < 384) k[i*192 + (c-192)] = val;
            else if (c < 576) v[i*192 + (c-384)] = val;
            else praw[ii][c-576] = val;
        }
    }
    __syncthreads();

    if (t < 192){
        #pragma unroll
        for (int ii=0;ii<II;ii++){
            size_t i = i0 + ii;
            const float* Ri = R + i*9;
            float R00=Ri[0],R01=Ri[1],R02=Ri[2];
            float R10=Ri[3],R11=Ri[4],R12=Ri[5];
            float R20=Ri[6],R21=Ri[7],R22=Ri[8];
            float t0=tv[i*3+0],t1=tv[i*3+1],t2=tv[i*3+2];
            int src; float* dst; int sqslot=-1;
            if (t < 48){ src = t*3; dst = gq + i*144 + t*3; sqslot = t; }
            else if (t < 96){ int u=t-48; src = 144+u*3; dst = gk + i*144 + u*3; sqslot = 48+u; }
            else { int u=t-96; src = 288+u*3; dst = gv + i*288 + u*3; }
            float x=praw[ii][src], y=praw[ii][src+1], zc=praw[ii][src+2];
            float g0 = fmaf(R00,x, fmaf(R01,y, fmaf(R02,zc, t0)));
            float g1 = fmaf(R10,x, fmaf(R11,y, fmaf(R12,zc, t1)));
            float g2 = fmaf(R20,x, fmaf(R21,y, fmaf(R22,zc, t2)));
            dst[0]=g0; dst[1]=g1; dst[2]=g2;
            if (sqslot >= 0) sq_pt[ii][sqslot] = g0*g0 + g1*g1 + g2*g2;
        }
    }
    __syncthreads();
    if (t < II*HD){
        int ii = t / HD, h = t % HD;
        float s1 = sq_pt[ii][h*4]+sq_pt[ii][h*4+1]+sq_pt[ii][h*4+2]+sq_pt[ii][h*4+3];
        float s2 = sq_pt[ii][48+h*4]+sq_pt[ii][48+h*4+1]+sq_pt[ii][48+h*4+2]+sq_pt[ii][48+h*4+3];
        sqq[(size_t)(i0+ii)*HD + h] = s1;
        sqk[(size_t)(i0+ii)*HD + h] = s2;
    }
}

// ---------------- K2: fused IPA (R12 phase A; phase B 64-row tiles — measured best 313 us) ----------------
__global__ __launch_bounds__(512) void k_ipa(
    const float* __restrict__ z, const float* __restrict__ Wb, const float* __restrict__ scale_head,
    const float* __restrict__ q, const float* __restrict__ k,
    const float* __restrict__ gq, const float* __restrict__ gk,
    const float* __restrict__ sqq, const float* __restrict__ sqk,
    const float* __restrict__ v, const float* __restrict__ gv,
    const float* __restrict__ R, const float* __restrict__ tv,
    float* __restrict__ att)
{
    __shared__ float ztile[2][64][CZD];   // 64KB: dbuf for both phases; exchange region between
    __shared__ float wbT[HD*CZD];         // [h][c]
    __shared__ float qloc[360];           // q(192) gq(144) sqq(12) sp(12)
    __shared__ float a_l[HD][NN];         // softmax'd attention, block-local
    __shared__ float so_l[288];

    int i = blockIdx.x, t = threadIdx.x;
    int wave = t >> 6, lane = t & 63;

    for (int idx=t; idx<HD*CZD; idx+=512){
        int h = idx >> 7, c = idx & 127;
        wbT[idx] = Wb[(size_t)c*HD + h];
    }
    if (t < 192) qloc[t] = q[(size_t)i*192 + t];
    else if (t < 336) qloc[t] = gq[(size_t)i*144 + (t-192)];
    else if (t < 348) qloc[t] = sqq[(size_t)i*HD + (t-336)];
    else if (t < 360){
        int h = t-348;
        float shv = scale_head[h];
        float sp = (shv > 20.f) ? shv : log1pf(__expf(shv));
        qloc[t] = SCALE_FRAME * sp;
    }

    const char* zi = (const char*)(z + (size_t)i*NN*CZD);
    float* zbase = &ztile[0][0][0];

#define STAGEL(JT, BUF) do { \
    const char* _zb = zi + (size_t)(JT)*32768; \
    char* _lb = (char*)zbase + (size_t)(BUF)*32768; \
    _Pragma("unroll") \
    for (int _m=0;_m<4;_m++){ \
        int _d = t*16 + _m*8192; \
        int _j = _d >> 9; \
        int _b = _d & 511; \
        int _sb = _b ^ ((_j & 31) << 4); \
        __builtin_amdgcn_global_load_lds((const __attribute__((address_space(1))) void*)(_zb + (size_t)_j*512 + _sb), \
            (__attribute__((address_space(3))) void*)(_lb + _d), 16, 0, 0); \
    } \
  } while(0)

#define STAGEB(JT, BUF) do { \
    const char* _zb = zi + (size_t)(JT)*32768; \
    char* _lb = (char*)zbase + (size_t)(BUF)*32768; \
    _Pragma("unroll") \
    for (int _m=0;_m<4;_m++){ \
        int _d = t*16 + _m*8192; \
        __builtin_amdgcn_global_load_lds((const __attribute__((address_space(1))) void*)(_zb + _d), \
            (__attribute__((address_space(3))) void*)(_lb + _d), 16, 0, 0); \
    } \
  } while(0)

    STAGEL(0, 0);

    int hg = (wave < 4) ? wave : (wave - 4);
    int h0 = hg * 3;
    float L[12][3];

    __syncthreads();   // wbT/qloc visible; STAGEL(0) drained

    {
        const float4* wb4 = (const float4*)wbT;
        const float4* qv4 = (const float4*)qloc;
        const float4* gq4 = (const float4*)(qloc + 192);
        int xoff = (lane & 31) << 4;

        for (int jt=0; jt<12; ++jt){
            int cur = jt & 1;
            if (jt+1 < 12) STAGEL(jt+1, cur^1);
            if (wave < 4){
                const char* zb = (const char*)(zbase + (size_t)cur*8192) + lane*512;
                float p0=0.f, p1=0.f, p2=0.f;
                #pragma unroll 8
                for (int c4=0; c4<32; ++c4){
                    float4 zv = *(const float4*)(zb + ((c4*16) ^ xoff));
                    p0 += dot4f(zv, wb4[(h0+0)*32 + c4]);
                    p1 += dot4f(zv, wb4[(h0+1)*32 + c4]);
                    p2 += dot4f(zv, wb4[(h0+2)*32 + c4]);
                }
                L[jt][0]=p0; L[jt][1]=p1; L[jt][2]=p2;
            } else {
                int jg = jt*64 + lane;
                const float4* kp  = (const float4*)(k  + (size_t)jg*192);
                const float4* gkp = (const float4*)(gk + (size_t)jg*144);
                #pragma unroll
                for (int hs=0; hs<3; ++hs){
                    int h = h0 + hs;
                    float sng = dot4f(qv4[h*4+0], kp[h*4+0]) + dot4f(qv4[h*4+1], kp[h*4+1])
                              + dot4f(qv4[h*4+2], kp[h*4+2]) + dot4f(qv4[h*4+3], kp[h*4+3]);
                    float fdot = dot4f(gq4[h*3+0], gkp[h*3+0]) + dot4f(gq4[h*3+1], gkp[h*3+1])
                               + dot4f(gq4[h*3+2], gkp[h*3+2]);
                    float d2 = qloc[336+h] + sqk[(size_t)jg*HD + h] - 2.0f*fdot;
                    L[jt][hs] = fmaf(SCALE_SINGLE, sng, qloc[348+h]*d2);
                }
            }
            __syncthreads();
        }
    }

    float* S_l = zbase;
    if (wave >= 4){
        int base = (hg*64 + lane) * 37;
        #pragma unroll
        for (int jt=0; jt<12; ++jt)
            #pragma unroll
            for (int hs=0; hs<3; ++hs)
                S_l[base + jt*3 + hs] = L[jt][hs];
    }
    __syncthreads();
    if (wave < 4){
        int base = (hg*64 + lane) * 37;
        #pragma unroll
        for (int jt=0; jt<12; ++jt)
            #pragma unroll
            for (int hs=0; hs<3; ++hs)
                L[jt][hs] += S_l[base + jt*3 + hs];

        #pragma unroll
        for (int hs=0; hs<3; ++hs){
            float m = -1e30f;
            #pragma unroll
            for (int jt=0; jt<12; ++jt) m = fmaxf(m, L[jt][hs]);
            #pragma unroll
            for (int off=32; off; off>>=1) m = fmaxf(m, __shfl_xor(m, off));
            float ssum = 0.f;
            #pragma unroll
            for (int jt=0; jt<12; ++jt){ float e = __expf(L[jt][hs]-m); L[jt][hs]=e; ssum += e; }
            #pragma unroll
            for (int off=32; off; off>>=1) ssum += __shfl_xor(ssum, off);
            float inv = 1.0f/ssum;
            #pragma unroll
            for (int jt=0; jt<12; ++jt){
                a_l[h0+hs][jt*64 + lane] = L[jt][hs]*inv;
            }
        }
    }
    __syncthreads();   // a_l complete; exchange region free for phase B

    // ---------------- phase B: 12 x 64-row linear tiles ----------------
    STAGEB(0, 0);

    int hs = 0;
    const float4* gsrc = nullptr;
    int gstride = 0;
    if (t < 384){ hs = t>>5; }
    else if (t < 432){ int u=t-384; hs = u>>2; gsrc = (const float4*)v  + hs*4 + (u&3); gstride = 48; }
    else if (t < 504){ int u=t-432; hs = u/6;  gsrc = (const float4*)gv + hs*6 + (u%6); gstride = 72; }
    float4 acc = {0.f,0.f,0.f,0.f};
    int c4 = t & 31;

    __syncthreads();   // STAGEB(0) drained

    for (int jt=0; jt<12; ++jt){
        int cur = jt & 1;
        if (jt+1 < 12) STAGEB(jt+1, cur^1);
        if (t < 384){
            const float4* arow4 = (const float4*)&a_l[hs][0];
            float4 af[16];
            #pragma unroll
            for (int m=0;m<16;m++) af[m] = arow4[jt*16 + m];
            const float4* zt4 = (const float4*)(zbase + (size_t)cur*8192);
            #pragma unroll
            for (int jj=0;jj<64;jj++){
                float aw = ((const float*)af)[jj];
                float4 zv = zt4[jj*32 + c4];
                acc.x = fmaf(aw, zv.x, acc.x);
                acc.y = fmaf(aw, zv.y, acc.y);
                acc.z = fmaf(aw, zv.z, acc.z);
                acc.w = fmaf(aw, zv.w, acc.w);
            }
        } else if (t < 504){
            const float* arow = &a_l[hs][0];
            #pragma unroll
            for (int jj=0;jj<64;jj++){
                int j = jt*64 + jj;
                float aw = arow[j];
                float4 sv = gsrc[(size_t)j*gstride];
                acc.x = fmaf(aw, sv.x, acc.x);
                acc.y = fmaf(aw, sv.y, acc.y);
                acc.z = fmaf(aw, sv.z, acc.z);
                acc.w = fmaf(aw, sv.w, acc.w);
            }
        }
        __syncthreads();
    }

    if (t < 384){
        float4* dst = (float4*)(att + (size_t)i*DOUT + 192) + (hs*32 + c4);
        *dst = acc;
    } else if (t < 432){
        int u = t-384;
        float4* dst = (float4*)(att + (size_t)i*DOUT) + u;
        *dst = acc;
    } else if (t < 504){
        int u = t-432;
        ((float4*)so_l)[u] = acc;
    }
    __syncthreads();
    if (t < 96){
        int h = t >> 3, p = t & 7;
        float d0 = so_l[h*24+p*3+0] - tv[(size_t)i*3+0];
        float d1 = so_l[h*24+p*3+1] - tv[(size_t)i*3+1];
        float d2 = so_l[h*24+p*3+2] - tv[(size_t)i*3+2];
        const float* Ri = R + (size_t)i*9;
        float l0 = fmaf(Ri[0],d0, fmaf(Ri[3],d1, Ri[6]*d2));
        float l1 = fmaf(Ri[1],d0, fmaf(Ri[4],d1, Ri[7]*d2));
        float l2 = fmaf(Ri[2],d0, fmaf(Ri[5],d1, Ri[8]*d2));
        size_t base = (size_t)i*DOUT;
        att[base + 1728 + p*36 + h*3 + 0] = l0;
        att[base + 1728 + p*36 + h*3 + 1] = l1;
        att[base + 1728 + p*36 + h*3 + 2] = l2;
        att[base + 2016 + p*12 + h] = sqrtf(l0*l0 + l1*l1 + l2*l2);
    }
#undef STAGEL
#undef STAGEB
}

// ---------------- K4: final projection att @ Wout(bf16) + bout ----------------
#define ROWS4 2
__global__ __launch_bounds__(384) void k_final(
    const float* __restrict__ att, const unsigned short* __restrict__ wobf,
    const float* __restrict__ bout, float* __restrict__ out)
{
    __shared__ float att_l[ROWS4*DOUT];
    int ib = blockIdx.x * ROWS4, t = threadIdx.x;
    for (int idx=t; idx<ROWS4*DOUT; idx+=384){
        att_l[idx] = att[(size_t)ib*DOUT + idx];
    }
    __syncthreads();
    float a0=0.f,a1=0.f,a2=0.f,a3=0.f;
    float b0=0.f,b1=0.f,b2=0.f,b3=0.f;
    #pragma unroll 4
    for (int d=0; d<DOUT; d+=4){
        float w0 = bf2f(wobf[(size_t)(d+0)*CSD + t]);
        float w1 = bf2f(wobf[(size_t)(d+1)*CSD + t]);
        float w2 = bf2f(wobf[(size_t)(d+2)*CSD + t]);
        float w3 = bf2f(wobf[(size_t)(d+3)*CSD + t]);
        a0 = fmaf(att_l[d+0], w0, a0);
        a1 = fmaf(att_l[d+1], w1, a1);
        a2 = fmaf(att_l[d+2], w2, a2);
        a3 = fmaf(att_l[d+3], w3, a3);
        b0 = fmaf(att_l[DOUT+d+0], w0, b0);
        b1 = fmaf(att_l[DOUT+d+1], w1, b1);
        b2 = fmaf(att_l[DOUT+d+2], w2, b2);
        b3 = fmaf(att_l[DOUT+d+3], w3, b3);
    }
    float bb = bout[t];
    out[(size_t)ib*CSD + t]     = bb + ((a0+a1)+(a2+a3));
    out[(size_t)(ib+1)*CSD + t] = bb + ((b0+b1)+(b2+b3));
}

extern "C" void kernel_launch(void* const* d_in, const int* in_sizes, int n_in,
                              void* d_out, int out_size, void* d_ws, size_t ws_size,
                              hipStream_t stream)
{
    const float* s   = (const float*)d_in[0];
    const float* z   = (const float*)d_in[1];
    const float* R   = (const float*)d_in[2];
    const float* tv  = (const float*)d_in[3];
    const float* Wq  = (const float*)d_in[4];
    const float* Wk  = (const float*)d_in[5];
    const float* Wv  = (const float*)d_in[6];
    const float* Wqp = (const float*)d_in[7];
    const float* Wkp = (const float*)d_in[8];
    const float* Wvp = (const float*)d_in[9];
    const float* Wb  = (const float*)d_in[10];
    const float* Wout= (const float*)d_in[11];
    const float* bout= (const float*)d_in[12];
    const float* sh  = (const float*)d_in[13];

    float* ws  = (float*)d_ws;
    float* q_  = ws;                 // 768*192
    float* k_  = q_  + 147456;       // 768*192
    float* v_  = k_  + 147456;       // 768*192
    float* gq_ = v_  + 147456;       // 768*144
    float* gk_ = gq_ + 110592;       // 768*144
    float* gv_ = gk_ + 110592;       // 768*288
    float* sqq_= gv_ + 221184;       // 768*12
    float* sqk_= sqq_ + 9216;        // 768*12
    float* att_= sqk_ + 9216;        // 768*2112
    unsigned short* wbf = (unsigned short*)(att_ + 1622016);  // 1253376 ushorts
    float* out = (float*)d_out;

    hipLaunchKernelGGL(k_conv,  dim3((NBF_TOTAL+255)/256), dim3(256), 0, stream,
                       Wq,Wk,Wv,Wqp,Wkp,Wvp,Wout, wbf);
    hipLaunchKernelGGL(k_proj,  dim3(NN/II), dim3(384), 0, stream,
                       s,R,tv, wbf, q_,k_,v_,gq_,gk_,gv_,sqq_,sqk_);
    hipLaunchKernelGGL(k_ipa,   dim3(NN),    dim3(512), 0, stream,
                       z,Wb,sh,q_,k_,gq_,gk_,sqq_,sqk_, v_,gv_,R,tv, att_);
    hipLaunchKernelGGL(k_final, dim3(NN/ROWS4), dim3(384), 0, stream,
                       att_, wbf + OFF_WOUT, bout, out);
}